// Round 2
// baseline (376.978 us; speedup 1.0000x reference)
//
#include <hip/hip_runtime.h>

// NetVLAD: N=16, C=1024, P=H*W=1024, K=32. Runtime dtype detection (fp32 vs
// bf16) because the harness dtype is ambiguous; fp32 internal math always.
#define NB   16
#define CC   1024
#define PP   1024
#define KK   32
#define EPSF 1e-12f

__device__ __forceinline__ float bf2f(unsigned short u) {
    union { unsigned int i; float f; } v;
    v.i = ((unsigned int)u) << 16;
    return v.f;
}
__device__ __forceinline__ unsigned short f2bf(float f) {
    union { float f; unsigned int i; } v;
    v.f = f;
    unsigned int i = v.i;
    return (unsigned short)((i + 0x7fffu + ((i >> 16) & 1u)) >> 16);  // RNE
}

template <typename T> struct IO;
template <> struct IO<float> {
    static __device__ __forceinline__ float  ld (const float* p) { return *p; }
    static __device__ __forceinline__ float4 ld4(const float* p) { return *(const float4*)p; }
    static __device__ __forceinline__ void   st (float* p, float v) { *p = v; }
};
template <> struct IO<unsigned short> {
    static __device__ __forceinline__ float  ld (const unsigned short* p) { return bf2f(*p); }
    static __device__ __forceinline__ float4 ld4(const unsigned short* p) {
        const ushort4 u = *(const ushort4*)p;
        return make_float4(bf2f(u.x), bf2f(u.y), bf2f(u.z), bf2f(u.w));
    }
    static __device__ __forceinline__ void   st (unsigned short* p, float v) { *p = f2bf(v); }
};

// ---------------------------------------------------------------------------
// Kernel 0: dtype detect. If x is really fp32, its even ushorts are random
// mantissa bits -> bf16 exponents > 0x9F appear w/ prob ~0.37 each. Genuine
// bf16 N(0,1) data never exceeds exponent 0x83. flag=1 => fp32.
// ---------------------------------------------------------------------------
__global__ __launch_bounds__(256) void k_detect(const unsigned short* __restrict__ xu,
                                                int* __restrict__ flag) {
    __shared__ int s;
    const int t = threadIdx.x;
    if (t == 0) s = 0;
    __syncthreads();
    int bad = 0;
    for (int i = t; i < 4096; i += 256) {
        const unsigned e = (xu[i] >> 7) & 0xFFu;
        if (e > 0x9Fu) bad = 1;
    }
    if (bad) atomicOr(&s, 1);
    __syncthreads();
    if (t == 0) flag[0] = s;
}

// ---------------------------------------------------------------------------
// Kernel 1: per-pixel L2 norm over channels -> rnorm[n*PP+p] = 1/max(||x||,eps)
// ---------------------------------------------------------------------------
template <typename T>
__device__ __forceinline__ void rnorm_body(const T* __restrict__ x,
                                           float* __restrict__ rnorm,
                                           float* lds, int b, int t) {
    const int pg = t & 15, cg = t >> 4;
    const T* xp = x + (size_t)(b >> 4) * (CC * PP) + ((b & 15) * 64) + pg * 4;
    float s0 = 0.f, s1 = 0.f, s2 = 0.f, s3 = 0.f;
    for (int c = cg; c < CC; c += 16) {
        const float4 a = IO<T>::ld4(xp + (size_t)c * PP);
        s0 += a.x * a.x; s1 += a.y * a.y; s2 += a.z * a.z; s3 += a.w * a.w;
    }
    lds[cg * 64 + pg * 4 + 0] = s0;
    lds[cg * 64 + pg * 4 + 1] = s1;
    lds[cg * 64 + pg * 4 + 2] = s2;
    lds[cg * 64 + pg * 4 + 3] = s3;
    __syncthreads();
    if (t < 64) {
        float s = 0.f;
        #pragma unroll
        for (int g = 0; g < 16; ++g) s += lds[g * 64 + t];
        rnorm[b * 64 + t] = 1.0f / fmaxf(sqrtf(s), EPSF);
    }
}
__global__ __launch_bounds__(256) void k_rnorm(const void* __restrict__ x,
                                               const int* __restrict__ flag,
                                               float* __restrict__ rnorm) {
    __shared__ __align__(16) float lds[16 * 64];
    const int b = blockIdx.x, t = threadIdx.x;
    if (*flag) rnorm_body<float>((const float*)x, rnorm, lds, b, t);
    else       rnorm_body<unsigned short>((const unsigned short*)x, rnorm, lds, b, t);
}

// ---------------------------------------------------------------------------
// Kernel 2: logits = (W @ x) * rnorm per pixel, softmax over K -> attn fp32;
// plus per-(n,k) attn-sums via one atomic per (block,k).
// smem carve: w[4608] l[2112] inv[64] rn[64] red[256] = 7104 floats
// ---------------------------------------------------------------------------
template <typename T>
__device__ __forceinline__ void logits_body(const T* __restrict__ x,
                                            const T* __restrict__ w,
                                            const float* __restrict__ rnorm,
                                            float* __restrict__ attn,
                                            float* __restrict__ asum,
                                            float* smem, int b, int t) {
    float* w_lds  = smem;            // [128][36]
    float* l_lds  = smem + 4608;     // [64][33]
    float* inv_lds = smem + 6720;    // [64]
    float* rn_lds = smem + 6784;     // [64]
    float* red    = smem + 6848;     // [256]
    const int n = b >> 4, pbase = (b & 15) * 64;
    const int pl = t & 63, k0 = (t >> 6) * 8;
    if (t < 64) rn_lds[t] = rnorm[n * PP + pbase + t];
    float acc[8];
    #pragma unroll
    for (int j = 0; j < 8; ++j) acc[j] = 0.f;
    const T* xp = x + (size_t)n * CC * PP + pbase + pl;
    for (int ch = 0; ch < 8; ++ch) {
        const int cb = ch * 128;
        __syncthreads();
        for (int idx = t; idx < 128 * 32; idx += 256) {
            const int ci = idx & 127, k = idx >> 7;
            w_lds[ci * 36 + k] = IO<T>::ld(&w[k * CC + cb + ci]);
        }
        __syncthreads();
        for (int ci = 0; ci < 128; ++ci) {
            const float xv = IO<T>::ld(&xp[(size_t)(cb + ci) * PP]);
            const float4* wp = (const float4*)&w_lds[ci * 36 + k0];
            const float4 w0 = wp[0], w1 = wp[1];
            acc[0] += xv * w0.x; acc[1] += xv * w0.y;
            acc[2] += xv * w0.z; acc[3] += xv * w0.w;
            acc[4] += xv * w1.x; acc[5] += xv * w1.y;
            acc[6] += xv * w1.z; acc[7] += xv * w1.w;
        }
    }
    const float rn = rn_lds[pl];
    __syncthreads();
    #pragma unroll
    for (int j = 0; j < 8; ++j) l_lds[pl * 33 + k0 + j] = acc[j] * rn;
    __syncthreads();
    if (t < 64) {
        float m = -1e30f;
        #pragma unroll
        for (int k = 0; k < KK; ++k) m = fmaxf(m, l_lds[t * 33 + k]);
        float s = 0.f;
        #pragma unroll
        for (int k = 0; k < KK; ++k) {
            const float e = expf(l_lds[t * 33 + k] - m);
            l_lds[t * 33 + k] = e;
            s += e;
        }
        inv_lds[t] = 1.0f / s;
    }
    __syncthreads();
    for (int idx = t; idx < KK * 64; idx += 256) {
        const int p = idx & 63, k = idx >> 6;
        attn[((size_t)n * KK + k) * PP + pbase + p] = l_lds[p * 33 + k] * inv_lds[p];
    }
    {
        const int k = t & 31, pg = t >> 5;
        float s = 0.f;
        #pragma unroll
        for (int j = 0; j < 8; ++j) {
            const int p = pg * 8 + j;
            s += l_lds[p * 33 + k] * inv_lds[p];
        }
        red[pg * 32 + k] = s;
    }
    __syncthreads();
    if (t < 32) {
        float s = 0.f;
        #pragma unroll
        for (int pg = 0; pg < 8; ++pg) s += red[pg * 32 + t];
        atomicAdd(&asum[n * KK + t], s);
    }
}
__global__ __launch_bounds__(256) void k_logits(const void* __restrict__ x,
                                                const void* __restrict__ w,
                                                const int* __restrict__ flag,
                                                const float* __restrict__ rnorm,
                                                float* __restrict__ attn,
                                                float* __restrict__ asum) {
    __shared__ __align__(16) float smem[7104];
    const int b = blockIdx.x, t = threadIdx.x;
    if (*flag) logits_body<float>((const float*)x, (const float*)w, rnorm, attn, asum, smem, b, t);
    else       logits_body<unsigned short>((const unsigned short*)x, (const unsigned short*)w,
                                           rnorm, attn, asum, smem, b, t);
}

// ---------------------------------------------------------------------------
// Kernel 3: vlad[n,k,c] = sum_p attn[k,p]*xn[c,p] - asum[k]*centroid[k,c];
// plus per-(n,k) sumsq via one atomic per (block,k).
// smem carve: xt[4160] a[2304] rn[1024] red2[256] = 7744 floats
// ---------------------------------------------------------------------------
template <typename T>
__device__ __forceinline__ void vlad_body(const T* __restrict__ x,
                                          const float* __restrict__ rnorm,
                                          const float* __restrict__ attn,
                                          const T* __restrict__ cent,
                                          const float* __restrict__ asum,
                                          float* __restrict__ vlad,
                                          float* __restrict__ ssqnk,
                                          float* smem, int b, int t) {
    float* xt     = smem;            // [64][65] (reused as reduce buf)
    float* a_lds  = smem + 4160;     // [64][36]
    float* rn_all = smem + 6464;     // [1024]
    float* red2   = smem + 7488;     // [256]
    const int n = b >> 4, cbase = (b & 15) * 64;
    const int cl = t & 63, k0 = (t >> 6) * 8;
    for (int i = t; i < PP; i += 256) rn_all[i] = rnorm[n * PP + i];
    float acc[8];
    #pragma unroll
    for (int j = 0; j < 8; ++j) acc[j] = 0.f;
    const size_t xbase = (size_t)n * CC * PP;
    for (int pc = 0; pc < 16; ++pc) {
        const int pb = pc * 64;
        __syncthreads();
        #pragma unroll
        for (int m = 0; m < 16; ++m) {
            const int idx = t + 256 * m;
            const int ci = idx >> 6, pj = idx & 63;
            const float v = IO<T>::ld(&x[xbase + (size_t)(cbase + ci) * PP + pb + pj]) * rn_all[pb + pj];
            xt[pj * 65 + ci] = v;
        }
        #pragma unroll
        for (int m = 0; m < 8; ++m) {
            const int idx = t + 256 * m;
            const int k = idx >> 6, pj = idx & 63;
            a_lds[pj * 36 + k] = attn[((size_t)n * KK + k) * PP + pb + pj];
        }
        __syncthreads();
        for (int pj = 0; pj < 64; ++pj) {
            const float xv = xt[pj * 65 + cl];
            const float4* ap = (const float4*)&a_lds[pj * 36 + k0];
            const float4 a0 = ap[0], a1 = ap[1];
            acc[0] += xv * a0.x; acc[1] += xv * a0.y;
            acc[2] += xv * a0.z; acc[3] += xv * a0.w;
            acc[4] += xv * a1.x; acc[5] += xv * a1.y;
            acc[6] += xv * a1.z; acc[7] += xv * a1.w;
        }
    }
    float vals[8];
    #pragma unroll
    for (int j = 0; j < 8; ++j) {
        const float A = asum[n * KK + k0 + j];
        const float cw = IO<T>::ld(&cent[(k0 + j) * CC + cbase + cl]);
        vals[j] = acc[j] - A * cw;
        vlad[((size_t)n * KK + k0 + j) * CC + cbase + cl] = vals[j];
    }
    __syncthreads();
    float* red = xt;
    #pragma unroll
    for (int j = 0; j < 8; ++j) red[(k0 + j) * 64 + cl] = vals[j] * vals[j];
    __syncthreads();
    {
        const int k = t >> 3, seg = t & 7;
        float s = 0.f;
        #pragma unroll
        for (int i = 0; i < 8; ++i) s += red[k * 64 + seg * 8 + i];
        red2[t] = s;
    }
    __syncthreads();
    if (t < 32) {
        float s = 0.f;
        #pragma unroll
        for (int g = 0; g < 8; ++g) s += red2[t * 8 + g];
        atomicAdd(&ssqnk[n * KK + t], s);
    }
}
__global__ __launch_bounds__(256) void k_vlad(const void* __restrict__ x,
                                              const int* __restrict__ flag,
                                              const float* __restrict__ rnorm,
                                              const float* __restrict__ attn,
                                              const void* __restrict__ cent,
                                              const float* __restrict__ asum,
                                              float* __restrict__ vlad,
                                              float* __restrict__ ssqnk) {
    __shared__ __align__(16) float smem[7744];
    const int b = blockIdx.x, t = threadIdx.x;
    if (*flag) vlad_body<float>((const float*)x, rnorm, attn, (const float*)cent,
                                asum, vlad, ssqnk, smem, b, t);
    else       vlad_body<unsigned short>((const unsigned short*)x, rnorm, attn,
                                         (const unsigned short*)cent, asum, vlad, ssqnk, smem, b, t);
}

// ---------------------------------------------------------------------------
// Kernel 4: per (n,k) intra rnorm; per n global rnorm (= sum_k ssq_k*r_k^2).
// ---------------------------------------------------------------------------
__global__ __launch_bounds__(64) void k_factors(const float* __restrict__ ssqnk,
                                                float* __restrict__ rintra,
                                                float* __restrict__ rglob) {
    const int n = blockIdx.x, t = threadIdx.x;
    const float s = (t < KK) ? ssqnk[n * KK + t] : 0.f;
    const float r = 1.0f / fmaxf(sqrtf(s), EPSF);
    if (t < KK) rintra[n * KK + t] = r;
    float g = s * r * r;
    for (int off = 32; off > 0; off >>= 1) g += __shfl_down(g, off, 64);
    if (t == 0) rglob[n] = 1.0f / fmaxf(sqrtf(g), EPSF);
}

// ---------------------------------------------------------------------------
// Kernel 5: out = vlad * rintra * rglob, cast to output dtype.
// ---------------------------------------------------------------------------
template <typename T>
__device__ __forceinline__ void out_body(const float* __restrict__ vlad,
                                         const float* __restrict__ rintra,
                                         const float* __restrict__ rglob,
                                         T* __restrict__ out, int b, int t) {
    const int n = b >> 5;
    const float f = rintra[b] * rglob[n];
    const float* vp = vlad + (size_t)b * CC;
    T* op = out + (size_t)b * CC;
    for (int c = t; c < CC; c += 256) IO<T>::st(&op[c], vp[c] * f);
}
__global__ __launch_bounds__(256) void k_out(const float* __restrict__ vlad,
                                             const float* __restrict__ rintra,
                                             const float* __restrict__ rglob,
                                             const int* __restrict__ flag,
                                             void* __restrict__ out) {
    const int b = blockIdx.x, t = threadIdx.x;
    if (*flag) out_body<float>(vlad, rintra, rglob, (float*)out, b, t);
    else       out_body<unsigned short>(vlad, rintra, rglob, (unsigned short*)out, b, t);
}

extern "C" void kernel_launch(void* const* d_in, const int* in_sizes, int n_in,
                              void* d_out, int out_size, void* d_ws, size_t ws_size,
                              hipStream_t stream) {
    const void* x    = d_in[0];
    const void* w    = d_in[1];
    const void* cent = d_in[2];

    float* ws     = (float*)d_ws;
    float* rnorm  = ws;                         // 16384
    float* attn   = rnorm + NB * PP;            // 524288
    float* vlad   = attn + NB * KK * PP;        // 524288
    float* asum   = vlad + NB * KK * CC;        // 512
    float* ssqnk  = asum + NB * KK;             // 512
    float* rintra = ssqnk + NB * KK;            // 512
    float* rglob  = rintra + NB * KK;           // 16
    int*   flag   = (int*)(rglob + NB);         // 1

    hipMemsetAsync(asum, 0, 2 * NB * KK * sizeof(float), stream);  // asum+ssqnk

    k_detect<<<1, 256, 0, stream>>>((const unsigned short*)x, flag);
    k_rnorm<<<256, 256, 0, stream>>>(x, flag, rnorm);
    k_logits<<<256, 256, 0, stream>>>(x, w, flag, rnorm, attn, asum);
    k_vlad<<<256, 256, 0, stream>>>(x, flag, rnorm, attn, cent, asum, vlad, ssqnk);
    k_factors<<<NB, 64, 0, stream>>>(ssqnk, rintra, rglob);
    k_out<<<NB * KK, 256, 0, stream>>>(vlad, rintra, rglob, flag, d_out);
}

// Round 4
// 125.470 us; speedup vs baseline: 3.0045x; 3.0045x over previous
//
#include <hip/hip_runtime.h>

// NetVLAD: N=16, C=1024, P=1024, K=32. MFMA bf16 for both GEMMs (NT layout).
// Runtime dtype detection (fp32 vs bf16 inputs); fp32 accumulate throughout.
#define NB   16
#define CC   1024
#define PP   1024
#define KK   32
#define EPSF 1e-12f

typedef __attribute__((ext_vector_type(8))) short  bf16x8;
typedef __attribute__((ext_vector_type(4))) float  f32x4;

__device__ __forceinline__ float bf2f(unsigned short u) {
    union { unsigned int i; float f; } v; v.i = ((unsigned int)u) << 16; return v.f;
}
__device__ __forceinline__ unsigned short f2bf(float f) {
    union { float f; unsigned int i; } v; v.f = f;
    return (unsigned short)((v.i + 0x7fffu + ((v.i >> 16) & 1u)) >> 16);  // RNE
}

template <typename T> struct IO;
template <> struct IO<float> {
    static __device__ __forceinline__ float  ld (const float* p) { return *p; }
    static __device__ __forceinline__ float4 ld4(const float* p) { return *(const float4*)p; }
};
template <> struct IO<unsigned short> {
    static __device__ __forceinline__ float  ld (const unsigned short* p) { return bf2f(*p); }
    static __device__ __forceinline__ float4 ld4(const unsigned short* p) {
        const ushort4 u = *(const ushort4*)p;
        return make_float4(bf2f(u.x), bf2f(u.y), bf2f(u.z), bf2f(u.w));
    }
};

// ---------------------------------------------------------------------------
// K0: dtype detect. fp32 data read as ushorts has random low-mantissa halves
// -> bf16-exponents > 0x9F appear w/ prob ~0.37 each over 4096 samples.
// ---------------------------------------------------------------------------
__global__ __launch_bounds__(256) void k_detect(const unsigned short* __restrict__ xu,
                                                int* __restrict__ flag) {
    __shared__ int s;
    const int t = threadIdx.x;
    if (t == 0) s = 0;
    __syncthreads();
    int bad = 0;
    for (int i = t; i < 4096; i += 256)
        if (((xu[i] >> 7) & 0xFFu) > 0x9Fu) bad = 1;
    if (bad) atomicOr(&s, 1);
    __syncthreads();
    if (t == 0) flag[0] = s;
}

// ---------------------------------------------------------------------------
// K1 (k_attn): per (n, 32-px tile): stage x transposed to LDS [px][c-chunk]
// (bf16), accumulate per-px sumsq, MFMA logits (M=32px, N=32k, Kdim=1024c),
// scale by rnorm, softmax over k, write attn bf16 + asum + rnorm.
// grid 512 = n*32 + pt, block 256.
// ---------------------------------------------------------------------------
template <typename T>
__device__ __forceinline__ void attn_body(const T* __restrict__ x,
                                          const T* __restrict__ w,
                                          float* __restrict__ rnorm_ws,
                                          unsigned short* __restrict__ attn_g,
                                          float* __restrict__ asum) {
    __shared__ __align__(16) unsigned short xt[32 * 136];    // [px][c] pad
    __shared__ __align__(16) unsigned short w_lds[32 * 136]; // [k][c] pad
    __shared__ float red[32 * 32];       // [c-group][px]
    __shared__ float lg[32 * 33];        // [px][k]
    __shared__ float inv_lds[32];
    __shared__ float rnorm_lds[32];
    const int b = blockIdx.x, t = threadIdx.x;
    const int n = b >> 5, pbase = (b & 31) * 32;
    const int lane = t & 63, wv = t >> 6;
    const int quad = lane >> 4, l15 = lane & 15;
    const int mt = wv & 1, nt = wv >> 1;     // wave -> (px-tile, k-tile)

    const size_t xb = (size_t)n * CC * PP + pbase;
    float ss0 = 0.f, ss1 = 0.f, ss2 = 0.f, ss3 = 0.f;
    f32x4 acc = {0.f, 0.f, 0.f, 0.f};

    const int pxg = 4 * (t & 7);     // this thread's 4 pixels (local)
    const int crow = t >> 3;          // base c-row (0..31)

    for (int ch = 0; ch < 8; ++ch) {
        const int c0 = ch * 128;
        __syncthreads();
        // stage x transposed: 32px x 128c, 4 passes
        #pragma unroll
        for (int pass = 0; pass < 4; ++pass) {
            const int cl = crow + 32 * pass;          // 0..127 chunk-local
            const float4 v = IO<T>::ld4(&x[xb + (size_t)(c0 + cl) * PP + pxg]);
            ss0 += v.x * v.x; ss1 += v.y * v.y; ss2 += v.z * v.z; ss3 += v.w * v.w;
            xt[(pxg + 0) * 136 + cl] = f2bf(v.x);
            xt[(pxg + 1) * 136 + cl] = f2bf(v.y);
            xt[(pxg + 2) * 136 + cl] = f2bf(v.z);
            xt[(pxg + 3) * 136 + cl] = f2bf(v.w);
        }
        // stage W chunk: 32k x 128c, thread: k=t>>3, 16 c's
        {
            const int k = t >> 3, cg = (t & 7) * 16;
            #pragma unroll
            for (int j = 0; j < 4; ++j) {
                const float4 v = IO<T>::ld4(&w[k * CC + c0 + cg + 4 * j]);
                ushort4 u;
                u.x = f2bf(v.x); u.y = f2bf(v.y); u.z = f2bf(v.z); u.w = f2bf(v.w);
                *(ushort4*)&w_lds[k * 136 + cg + 4 * j] = u;
            }
        }
        __syncthreads();
        // MFMA: 4 ksteps of 32 c
        #pragma unroll
        for (int ks = 0; ks < 4; ++ks) {
            const bf16x8 av = *(const bf16x8*)&xt[(mt * 16 + l15) * 136 + ks * 32 + quad * 8];
            const bf16x8 bv = *(const bf16x8*)&w_lds[(nt * 16 + l15) * 136 + ks * 32 + quad * 8];
            acc = __builtin_amdgcn_mfma_f32_16x16x32_bf16(av, bv, acc, 0, 0, 0);
        }
    }
    // reduce sumsq: red[c-group][px]
    red[crow * 32 + pxg + 0] = ss0;
    red[crow * 32 + pxg + 1] = ss1;
    red[crow * 32 + pxg + 2] = ss2;
    red[crow * 32 + pxg + 3] = ss3;
    __syncthreads();
    if (t < 32) {
        float s = 0.f;
        #pragma unroll
        for (int g = 0; g < 32; ++g) s += red[g * 32 + t];
        const float r = 1.0f / fmaxf(sqrtf(s), EPSF);
        rnorm_lds[t] = r;
        rnorm_ws[n * PP + pbase + t] = r;
    }
    __syncthreads();
    // write logits (scaled by rnorm) to LDS: D row=px(local in tile), col=k
    #pragma unroll
    for (int reg = 0; reg < 4; ++reg) {
        const int px = mt * 16 + quad * 4 + reg;
        lg[px * 33 + nt * 16 + l15] = acc[reg] * rnorm_lds[px];
    }
    __syncthreads();
    if (t < 32) {
        float m = -1e30f;
        #pragma unroll
        for (int k = 0; k < KK; ++k) m = fmaxf(m, lg[t * 33 + k]);
        float s = 0.f;
        #pragma unroll
        for (int k = 0; k < KK; ++k) {
            const float e = expf(lg[t * 33 + k] - m);
            lg[t * 33 + k] = e;
            s += e;
        }
        inv_lds[t] = 1.0f / s;
    }
    __syncthreads();
    // write attn bf16 (thread: k=t>>3, 4 px) + asum atomics
    {
        const int k = t >> 3;
        float s = 0.f;
        ushort4 u;
        float vv[4];
        #pragma unroll
        for (int j = 0; j < 4; ++j) {
            const int px = pxg + j;
            vv[j] = lg[px * 33 + k] * inv_lds[px];
        }
        u.x = f2bf(vv[0]); u.y = f2bf(vv[1]); u.z = f2bf(vv[2]); u.w = f2bf(vv[3]);
        s = bf2f(u.x) + bf2f(u.y) + bf2f(u.z) + bf2f(u.w);
        *(ushort4*)&attn_g[((size_t)n * KK + k) * PP + pbase + pxg] = u;
        s += __shfl_xor(s, 1, 64);
        s += __shfl_xor(s, 2, 64);
        s += __shfl_xor(s, 4, 64);
        if ((t & 7) == 0) atomicAdd(&asum[n * KK + k], s);
    }
}
__global__ __launch_bounds__(256) void k_attn(const void* __restrict__ x,
                                              const void* __restrict__ w,
                                              const int* __restrict__ flag,
                                              float* __restrict__ rnorm_ws,
                                              unsigned short* __restrict__ attn_g,
                                              float* __restrict__ asum) {
    if (*flag) attn_body<float>((const float*)x, (const float*)w, rnorm_ws, attn_g, asum);
    else       attn_body<unsigned short>((const unsigned short*)x, (const unsigned short*)w,
                                         rnorm_ws, attn_g, asum);
}

// ---------------------------------------------------------------------------
// K2 (k_vlad): per (n, 64-c tile): MFMA vlad (M=32k, N=64c, Kdim=1024p).
// A=attn[k][p] bf16 staged, B=x*rnorm[c][p] bf16 staged (both p-contiguous).
// Epilogue: - asum*cent, write vlad fp32, per-k sumsq atomics.
// grid 256 = n*16 + ct, block 256.
// ---------------------------------------------------------------------------
template <typename T>
__device__ __forceinline__ void vlad_body(const T* __restrict__ x,
                                          const T* __restrict__ cent,
                                          const float* __restrict__ rnorm_ws,
                                          const unsigned short* __restrict__ attn_g,
                                          const float* __restrict__ asum,
                                          float* __restrict__ vlad,
                                          float* __restrict__ ssqnk) {
    __shared__ __align__(16) unsigned short xt[64 * 136];    // [c][p] pad
    __shared__ __align__(16) unsigned short at_lds[32 * 136];// [k][p] pad
    __shared__ float asum_lds[32];
    __shared__ float ssq_lds[32];
    const int b = blockIdx.x, t = threadIdx.x;
    const int n = b >> 4, cbase = (b & 15) * 64;
    const int lane = t & 63, wv = t >> 6;
    const int quad = lane >> 4, l15 = lane & 15;
    const int mt = wv & 1, nt0 = (wv >> 1) * 2, nt1 = nt0 + 1;

    if (t < 32) { asum_lds[t] = asum[n * KK + t]; ssq_lds[t] = 0.f; }

    f32x4 acc0 = {0.f, 0.f, 0.f, 0.f}, acc1 = {0.f, 0.f, 0.f, 0.f};
    const size_t xb = (size_t)n * CC * PP + (size_t)cbase * PP;

    for (int pc = 0; pc < 8; ++pc) {
        const int p0 = pc * 128;
        __syncthreads();
        // stage attn chunk: 32k x 128p; thread covers 16 bf16 = 2 x uint4
        {
            const int k = t >> 3, pg = (t & 7) * 16;
            const size_t base = ((size_t)n * KK + k) * PP + p0 + pg;
            const uint4 u0 = *(const uint4*)&attn_g[base];
            const uint4 u1 = *(const uint4*)&attn_g[base + 8];
            *(uint4*)&at_lds[k * 136 + pg]     = u0;
            *(uint4*)&at_lds[k * 136 + pg + 8] = u1;
        }
        // stage x-hat chunk: 64c x 128p; thread: 4 px, 8 c-rows
        {
            const int pg = 4 * (t & 31);
            const float4 rn = *(const float4*)&rnorm_ws[n * PP + p0 + pg];
            #pragma unroll
            for (int pass = 0; pass < 8; ++pass) {
                const int ci = (t >> 5) + 8 * pass;
                const float4 v = IO<T>::ld4(&x[xb + (size_t)ci * PP + p0 + pg]);
                ushort4 u;
                u.x = f2bf(v.x * rn.x); u.y = f2bf(v.y * rn.y);
                u.z = f2bf(v.z * rn.z); u.w = f2bf(v.w * rn.w);
                *(ushort4*)&xt[ci * 136 + pg] = u;
            }
        }
        __syncthreads();
        #pragma unroll
        for (int ks = 0; ks < 4; ++ks) {
            const bf16x8 av  = *(const bf16x8*)&at_lds[(mt * 16 + l15) * 136 + ks * 32 + quad * 8];
            const bf16x8 bv0 = *(const bf16x8*)&xt[(nt0 * 16 + l15) * 136 + ks * 32 + quad * 8];
            const bf16x8 bv1 = *(const bf16x8*)&xt[(nt1 * 16 + l15) * 136 + ks * 32 + quad * 8];
            acc0 = __builtin_amdgcn_mfma_f32_16x16x32_bf16(av, bv0, acc0, 0, 0, 0);
            acc1 = __builtin_amdgcn_mfma_f32_16x16x32_bf16(av, bv1, acc1, 0, 0, 0);
        }
    }
    __syncthreads();
    // epilogue: D row = k(local), col = c(local)
    const int c0g = cbase + nt0 * 16 + l15, c1g = cbase + nt1 * 16 + l15;
    #pragma unroll
    for (int reg = 0; reg < 4; ++reg) {
        const int k = mt * 16 + quad * 4 + reg;
        const float A = asum_lds[k];
        const float v0 = acc0[reg] - A * IO<T>::ld(&cent[k * CC + c0g]);
        const float v1 = acc1[reg] - A * IO<T>::ld(&cent[k * CC + c1g]);
        vlad[((size_t)n * KK + k) * CC + c0g] = v0;
        vlad[((size_t)n * KK + k) * CC + c1g] = v1;
        float s = v0 * v0 + v1 * v1;
        s += __shfl_xor(s, 1, 64);
        s += __shfl_xor(s, 2, 64);
        s += __shfl_xor(s, 4, 64);
        s += __shfl_xor(s, 8, 64);
        if (l15 == 0) atomicAdd(&ssq_lds[k], s);
    }
    __syncthreads();
    if (t < 32) atomicAdd(&ssqnk[n * KK + t], ssq_lds[t]);
}
__global__ __launch_bounds__(256) void k_vlad(const void* __restrict__ x,
                                              const void* __restrict__ cent,
                                              const int* __restrict__ flag,
                                              const float* __restrict__ rnorm_ws,
                                              const unsigned short* __restrict__ attn_g,
                                              const float* __restrict__ asum,
                                              float* __restrict__ vlad,
                                              float* __restrict__ ssqnk) {
    if (*flag) vlad_body<float>((const float*)x, (const float*)cent, rnorm_ws, attn_g,
                                asum, vlad, ssqnk);
    else       vlad_body<unsigned short>((const unsigned short*)x, (const unsigned short*)cent,
                                         rnorm_ws, attn_g, asum, vlad, ssqnk);
}

// ---------------------------------------------------------------------------
// K3: per (n,k) intra rnorm; per n global rnorm (sum_k ssq_k * r_k^2).
// ---------------------------------------------------------------------------
__global__ __launch_bounds__(64) void k_factors(const float* __restrict__ ssqnk,
                                                float* __restrict__ rintra,
                                                float* __restrict__ rglob) {
    const int n = blockIdx.x, t = threadIdx.x;
    const float s = (t < KK) ? ssqnk[n * KK + t] : 0.f;
    const float r = 1.0f / fmaxf(sqrtf(s), EPSF);
    if (t < KK) rintra[n * KK + t] = r;
    float g = s * r * r;
    for (int off = 32; off > 0; off >>= 1) g += __shfl_down(g, off, 64);
    if (t == 0) rglob[n] = 1.0f / fmaxf(sqrtf(g), EPSF);
}

// ---------------------------------------------------------------------------
// K4: out = vlad * rintra * rglob, cast to out dtype. grid N*K, 256 thr.
// ---------------------------------------------------------------------------
__global__ __launch_bounds__(256) void k_out(const float* __restrict__ vlad,
                                             const float* __restrict__ rintra,
                                             const float* __restrict__ rglob,
                                             const int* __restrict__ flag,
                                             void* __restrict__ out) {
    const int b = blockIdx.x, t = threadIdx.x;
    const float f = rintra[b] * rglob[b >> 5];
    const float4 v = ((const float4*)(vlad + (size_t)b * CC))[t];
    if (*flag) {
        float4 o; o.x = v.x * f; o.y = v.y * f; o.z = v.z * f; o.w = v.w * f;
        ((float4*)((float*)out + (size_t)b * CC))[t] = o;
    } else {
        ushort4 u;
        u.x = f2bf(v.x * f); u.y = f2bf(v.y * f);
        u.z = f2bf(v.z * f); u.w = f2bf(v.w * f);
        ((ushort4*)((unsigned short*)out + (size_t)b * CC))[t] = u;
    }
}

extern "C" void kernel_launch(void* const* d_in, const int* in_sizes, int n_in,
                              void* d_out, int out_size, void* d_ws, size_t ws_size,
                              hipStream_t stream) {
    const void* x    = d_in[0];
    const void* w    = d_in[1];
    const void* cent = d_in[2];

    float* ws       = (float*)d_ws;
    float* rnorm_ws = ws;                          // 16384
    float* vlad     = rnorm_ws + NB * PP;          // 524288
    float* asum     = vlad + NB * KK * CC;         // 512
    float* ssqnk    = asum + NB * KK;              // 512
    float* rintra   = ssqnk + NB * KK;             // 512
    float* rglob    = rintra + NB * KK;            // 16
    int*   flag     = (int*)(rglob + NB);          // 1 (+ pad)
    unsigned short* attn_g = (unsigned short*)(flag + 4);   // 512K ushorts

    hipMemsetAsync(asum, 0, 2 * NB * KK * sizeof(float), stream);  // asum+ssqnk

    k_detect<<<1, 256, 0, stream>>>((const unsigned short*)x, flag);
    k_attn<<<NB * 32, 256, 0, stream>>>(x, w, flag, rnorm_ws, attn_g, asum);
    k_vlad<<<NB * 16, 256, 0, stream>>>(x, cent, flag, rnorm_ws, attn_g, asum, vlad, ssqnk);
    k_factors<<<NB, 64, 0, stream>>>(ssqnk, rintra, rglob);
    k_out<<<NB * KK, 256, 0, stream>>>(vlad, rintra, rglob, flag, d_out);
}